// Round 3
// baseline (438.611 us; speedup 1.0000x reference)
//
#include <hip/hip_runtime.h>

// S_GC_att_A round 3: z-first fused kernel (R2 + LDS-overlap fix).
//   z[ci,tw] = sum_v x[ci,t,v]*M_k[v,w]   (MFMA, K padded 22->32)
//   out[c,tw] += sum_ci Wk[c,ci]*z[ci,tw] (MFMA, ci in 4 chunks of 64)
//   bias: out += sum_k b[k*256+c]*S_k[w]  (epilogue)
// R3 fix: R2 placed Ss at Ms+10752 but Ms is MROWS(176)*32*2 = 11264 B ->
//   512 B overlap; Ms zero-init raced with Ss writes -> bias corruption
//   (absmax 0.98). Ss now at Ms+11264; smem 37536 B.

#define TT    4
#define NTW   88     // TT*22
#define XSTR  104    // Xs row stride in bf16 (4*24 + 8 pad; 208 B -> 2-way banks, free)
#define MROWS 176    // 7*24 + 8 pad rows
#define CHUNK 64
#define WB_BYTES (7 * 256 * 256 * 2)

typedef __attribute__((ext_vector_type(8))) __bf16    bf16x8;
typedef __attribute__((ext_vector_type(4))) float     f32x4;
typedef __attribute__((ext_vector_type(8))) short     s16x8;
typedef __attribute__((ext_vector_type(2))) unsigned  u32x2;
typedef __attribute__((ext_vector_type(4))) unsigned  u32x4;

__device__ __forceinline__ unsigned short f2bf_rn(float f) {  // RNE
  union { float f; unsigned u; } x; x.f = f;
  return (unsigned short)((x.u + 0x7FFFu + ((x.u >> 16) & 1u)) >> 16);
}
__device__ __forceinline__ unsigned pk_rh(float a, float b) { // lo=bf(a), hi=bf(b), round-half-up
  unsigned ua = __builtin_bit_cast(unsigned, a) + 0x8000u;
  unsigned ub = __builtin_bit_cast(unsigned, b) + 0x8000u;
  return __builtin_amdgcn_perm(ub, ua, 0x07060302);           // one v_perm_b32
}

// ---- W fp32 -> bf16 (RNE) into workspace; 224 blocks * 256 thr * 8 elems = 458752 exact
__global__ void wconv(const float* __restrict__ W, unsigned short* __restrict__ Wb) {
  int i = (blockIdx.x * 256 + threadIdx.x) * 8;
  float4 a = *(const float4*)(W + i);
  float4 c = *(const float4*)(W + i + 4);
  s16x8 r;
  r[0] = (short)f2bf_rn(a.x); r[1] = (short)f2bf_rn(a.y);
  r[2] = (short)f2bf_rn(a.z); r[3] = (short)f2bf_rn(a.w);
  r[4] = (short)f2bf_rn(c.x); r[5] = (short)f2bf_rn(c.y);
  r[6] = (short)f2bf_rn(c.z); r[7] = (short)f2bf_rn(c.w);
  *(s16x8*)(Wb + i) = r;
}

__device__ __forceinline__ bf16x8 ldw_f32(const float* p) {   // fallback: fp32 W, half-up pack
  float4 a = *(const float4*)(p);
  float4 c = *(const float4*)(p + 4);
  u32x4 q;
  q[0] = pk_rh(a.x, a.y); q[1] = pk_rh(a.z, a.w);
  q[2] = pk_rh(c.x, c.y); q[3] = pk_rh(c.z, c.w);
  return __builtin_bit_cast(bf16x8, q);
}

template <bool USE_WB>
__global__ __launch_bounds__(256, 3)
void sgc_fused(const float* __restrict__ x, const float* __restrict__ Ag,
               const float* __restrict__ attA, const float* __restrict__ W,
               const unsigned short* __restrict__ Wb, const float* __restrict__ b,
               float* __restrict__ out) {
  const int tt   = blockIdx.x;        // 0..127  (t-tile of 4)
  const int n    = blockIdx.y;        // 0..7
  const int tid  = threadIdx.x;
  const int wave = tid >> 6;
  const int lane = tid & 63;
  const int l15  = lane & 15;
  const int l4   = lane >> 4;

  // LDS: Xs [64][104] bf16 @0 (13312) | Zs [96][64] bf16 swizzled @13312 (12288)
  //      Ms [176][32] bf16 @25600 (11264) | Ss [7][24] f32 @36864 (672) = 37536 B
  __shared__ __align__(16) char smem[37536];
  unsigned short* Xs = (unsigned short*)(smem);
  unsigned short* Zs = (unsigned short*)(smem + 13312);
  unsigned short* Ms = (unsigned short*)(smem + 25600);
  float*          Ss = (float*)(smem + 36864);   // = 25600 + MROWS*32*2, NO overlap with Ms
  float*          B2 = (float*)(smem);           // epilogue reuse of Xs+Zs: [256][25] f32 = 25600

  f32x4 acc[4][6];
  #pragma unroll
  for (int i = 0; i < 4; ++i)
    #pragma unroll
    for (int j = 0; j < 6; ++j)
      acc[i][j] = (f32x4){0.f, 0.f, 0.f, 0.f};

  // ---- block init: M~[k][w][v] = M_k[v][w] bf16, zero-padded ----
  for (int i = tid; i < MROWS * 32; i += 256) {
    int row = i >> 5, v = i & 31;
    int k = row / 24, w = row - k * 24;
    float val = 0.f;
    if (row < 168 && w < 22 && v < 22)
      val = (k < 3) ? Ag[(k * 22 + v) * 22 + w]
                    : attA[(((n << 2) + (k - 3)) * 22 + v) * 22 + w];
    Ms[i] = f2bf_rn(val);
  }
  if (tid < 168) {                               // S[k][w] = sum_v M_k[v][w] (fp32 exact)
    int k = tid / 24, w = tid - k * 24;
    float s = 0.f;
    if (w < 22)
      for (int v = 0; v < 22; ++v)
        s += (k < 3) ? Ag[(k * 22 + v) * 22 + w]
                     : attA[(((n << 2) + (k - 3)) * 22 + v) * 22 + w];
    Ss[tid] = s;
  }
  for (int i = tid; i < 512; i += 256) Zs[88 * CHUNK + i] = 0;   // Ntile-5 pad rows
  for (int i = tid; i < 64 * XSTR / 2; i += 256) ((unsigned*)Xs)[i] = 0; // pads must be 0 not NaN
  __syncthreads();

  for (int chunk = 0; chunk < 4; ++chunk) {
    // ---- stage x[n, chunk*64..+64, tt*4..+4, :] -> Xs bf16 [ci][t*24+v] ----
    for (int i = tid; i < CHUNK * 22; i += 256) {
      int ci = i / 22, q = i - ci * 22;
      const float4 f4 = *(const float4*)(x + (size_t)((n * 256 + chunk * CHUNK + ci) * 11264)
                                           + tt * NTW + q * 4);
      float vv[4] = {f4.x, f4.y, f4.z, f4.w};
      int tv0 = q * 4;
      #pragma unroll
      for (int j = 0; j < 4; ++j) {
        int tv = tv0 + j;
        int t = tv / 22, v = tv - t * 22;
        Xs[ci * XSTR + t * 24 + v] = f2bf_rn(vv[j]);
      }
    }
    __syncthreads();

    for (int k = 0; k < 7; ++k) {
      // ---- W-frag prefetch (global, LDS-independent; drained by the barrier below) ----
      bf16x8 wf[2][4];
      #pragma unroll
      for (int s = 0; s < 2; ++s)
        #pragma unroll
        for (int mi = 0; mi < 4; ++mi) {
          int c = (wave * 4 + mi) * 16 + l15;
          size_t idx = (size_t)((k * 256 + c) * 256) + chunk * CHUNK + s * 32 + l4 * 8;
          wf[s][mi] = USE_WB ? *(const bf16x8*)(Wb + idx) : ldw_f32(W + idx);
        }

      // ---- z phase: z[ci,w] = X[ci,v] @ M_k[v,w]; wave owns ci-rows [wave*16, +16) ----
      bf16x8 bm0 = *(const bf16x8*)(&Ms[(k * 24 + l15) * 32 + l4 * 8]);
      bf16x8 bm1 = *(const bf16x8*)(&Ms[(k * 24 + 16 + l15) * 32 + l4 * 8]);
      const int ci0 = wave * 16 + l4 * 4;
      const int cb  = ci0 >> 3, sub = ci0 & 7;
      #pragma unroll
      for (int th = 0; th < 2; ++th) {           // t in halves: caps live zt at 16 VGPRs
        f32x4 zt[2][2];
        #pragma unroll
        for (int t2 = 0; t2 < 2; ++t2) {
          int t = th * 2 + t2;
          bf16x8 ax = *(const bf16x8*)(&Xs[(wave * 16 + l15) * XSTR + t * 24 + l4 * 8]);
          zt[t2][0] = __builtin_amdgcn_mfma_f32_16x16x32_bf16(ax, bm0, (f32x4){0.f,0.f,0.f,0.f}, 0, 0, 0);
          zt[t2][1] = __builtin_amdgcn_mfma_f32_16x16x32_bf16(ax, bm1, (f32x4){0.f,0.f,0.f,0.f}, 0, 0, 0);
        }
        #pragma unroll
        for (int t2 = 0; t2 < 2; ++t2) {
          int t = th * 2 + t2;
          #pragma unroll
          for (int ni = 0; ni < 2; ++ni) {
            int w = ni * 16 + l15;
            if (w < 22) {
              int tw = t * 22 + w;
              int eo = tw * CHUNK + ((cb ^ (tw & 7)) << 3) + sub;
              f32x4 z = zt[t2][ni];
              u32x2 p; p[0] = pk_rh(z[0], z[1]); p[1] = pk_rh(z[2], z[3]);
              *(u32x2*)(&Zs[eo]) = p;            // 8 B, 8-B aligned, ~2-way banks
            }
          }
        }
      }
      __syncthreads();

      // ---- main GEMM: out[c,tw] += Wk[c, ci-chunk] @ z ----
      #pragma unroll
      for (int s = 0; s < 2; ++s) {
        int cb2 = (s << 2) + l4;
        #pragma unroll
        for (int ni = 0; ni < 6; ++ni) {
          int tw = ni * 16 + l15;
          bf16x8 zf = *(const bf16x8*)(&Zs[tw * CHUNK + ((cb2 ^ (tw & 7)) << 3)]);
          #pragma unroll
          for (int mi = 0; mi < 4; ++mi)
            acc[mi][ni] = __builtin_amdgcn_mfma_f32_16x16x32_bf16(wf[s][mi], zf, acc[mi][ni], 0, 0, 0);
        }
      }
      __syncthreads();   // protects Zs overwrite (next k) / Xs overwrite (next chunk)
    }
  }

  // ---- bias2[c][w] = sum_k b[k*256+c] * S_k[w]  (Xs+Zs dead -> reuse as B2) ----
  for (int i = tid; i < 256 * 22; i += 256) {
    int c = i / 22, w = i - c * 22;
    float s = 0.f;
    #pragma unroll
    for (int k = 0; k < 7; ++k) s += b[k * 256 + c] * Ss[k * 24 + w];
    B2[c * 25 + w] = s;
  }
  __syncthreads();

  // ---- epilogue: bias + store. C-layout: col=tw, row=l4*4+r ----
  int tg0 = tt * TT;
  #pragma unroll
  for (int ni = 0; ni < 6; ++ni) {
    int tw = ni * 16 + l15;
    if (tw < NTW) {
      int t = tw / 22, w = tw - t * 22;
      #pragma unroll
      for (int mi = 0; mi < 4; ++mi) {
        int c0 = (wave * 4 + mi) * 16 + l4 * 4;
        #pragma unroll
        for (int r = 0; r < 4; ++r) {
          int c = c0 + r;
          out[(size_t)((n * 256 + c) * 512 + tg0 + t) * 22 + w] = acc[mi][ni][r] + B2[c * 25 + w];
        }
      }
    }
  }
}

extern "C" void kernel_launch(void* const* d_in, const int* in_sizes, int n_in,
                              void* d_out, int out_size, void* d_ws, size_t ws_size,
                              hipStream_t stream) {
  (void)in_sizes; (void)n_in; (void)out_size;
  const float* x    = (const float*)d_in[0];
  const float* Ag   = (const float*)d_in[1];
  const float* attA = (const float*)d_in[2];
  const float* W    = (const float*)d_in[3];
  const float* b    = (const float*)d_in[4];
  float* out = (float*)d_out;
  dim3 grid(128, 8, 1);
  bool use_wb = (d_ws != nullptr) && (ws_size >= (size_t)WB_BYTES);
  if (use_wb) {
    unsigned short* Wb = (unsigned short*)d_ws;
    wconv<<<224, 256, 0, stream>>>(W, Wb);
    sgc_fused<true><<<grid, 256, 0, stream>>>(x, Ag, attA, W, Wb, b, out);
  } else {
    sgc_fused<false><<<grid, 256, 0, stream>>>(x, Ag, attA, W, nullptr, b, out);
  }
}

// Round 4
// 309.200 us; speedup vs baseline: 1.4185x; 1.4185x over previous
//
#include <hip/hip_runtime.h>

// S_GC_att_A round 4: z-first fused kernel, occupancy-targeted split.
// R3 post-mortem: 84 VGPR + 96 AGPR(acc[4][6]) = 180 regs -> 2 waves/SIMD hard cap;
// dur stuck at 336us with MfmaUtil 12.7% == pure-MFMA/dur exactly -> stall-bound.
// R4: split c-dim across 2 blocks (128 c each, grid 2048). acc -> 48 AGPR,
// wf -> 16 VGPR; target 4 waves/SIMD, 4 blocks/CU (LDS 37.5KB). z/staging/setup
// duplicated 2x (+14% MFMA total) traded for 2x latency-hiding.

#define TT    4
#define NTW   88     // TT*22
#define XSTR  104    // Xs row stride in bf16 (4*24 + 8 pad)
#define MROWS 176    // 7*24 + 8 pad rows
#define CHUNK 64
#define WB_BYTES (7 * 256 * 256 * 2)

typedef __attribute__((ext_vector_type(8))) __bf16    bf16x8;
typedef __attribute__((ext_vector_type(4))) float     f32x4;
typedef __attribute__((ext_vector_type(8))) short     s16x8;
typedef __attribute__((ext_vector_type(2))) unsigned  u32x2;
typedef __attribute__((ext_vector_type(4))) unsigned  u32x4;

__device__ __forceinline__ unsigned short f2bf_rn(float f) {  // RNE
  union { float f; unsigned u; } x; x.f = f;
  return (unsigned short)((x.u + 0x7FFFu + ((x.u >> 16) & 1u)) >> 16);
}
__device__ __forceinline__ unsigned pk_rh(float a, float b) { // lo=bf(a), hi=bf(b), half-up
  unsigned ua = __builtin_bit_cast(unsigned, a) + 0x8000u;
  unsigned ub = __builtin_bit_cast(unsigned, b) + 0x8000u;
  return __builtin_amdgcn_perm(ub, ua, 0x07060302);           // one v_perm_b32
}

// ---- W fp32 -> bf16 (RNE) into workspace; 224*256*8 = 458752 elems exact
__global__ void wconv(const float* __restrict__ W, unsigned short* __restrict__ Wb) {
  int i = (blockIdx.x * 256 + threadIdx.x) * 8;
  float4 a = *(const float4*)(W + i);
  float4 c = *(const float4*)(W + i + 4);
  s16x8 r;
  r[0] = (short)f2bf_rn(a.x); r[1] = (short)f2bf_rn(a.y);
  r[2] = (short)f2bf_rn(a.z); r[3] = (short)f2bf_rn(a.w);
  r[4] = (short)f2bf_rn(c.x); r[5] = (short)f2bf_rn(c.y);
  r[6] = (short)f2bf_rn(c.z); r[7] = (short)f2bf_rn(c.w);
  *(s16x8*)(Wb + i) = r;
}

__device__ __forceinline__ bf16x8 ldw_f32(const float* p) {   // fallback path
  float4 a = *(const float4*)(p);
  float4 c = *(const float4*)(p + 4);
  u32x4 q;
  q[0] = pk_rh(a.x, a.y); q[1] = pk_rh(a.z, a.w);
  q[2] = pk_rh(c.x, c.y); q[3] = pk_rh(c.z, c.w);
  return __builtin_bit_cast(bf16x8, q);
}

template <bool USE_WB>
__global__ __launch_bounds__(256, 4)
void sgc_fused(const float* __restrict__ x, const float* __restrict__ Ag,
               const float* __restrict__ attA, const float* __restrict__ W,
               const unsigned short* __restrict__ Wb, const float* __restrict__ b,
               float* __restrict__ out) {
  const int tt   = blockIdx.x;        // 0..127  (t-tile of 4)
  const int n    = blockIdx.y;        // 0..7
  const int ch   = blockIdx.z;        // 0..1    (c-half: this block owns c in [ch*128, +128))
  const int tid  = threadIdx.x;
  const int wave = tid >> 6;
  const int lane = tid & 63;
  const int l15  = lane & 15;
  const int l4   = lane >> 4;

  // LDS: Xs [64][104] bf16 @0 (13312) | Zs [96][64] bf16 swizzled @13312 (12288)
  //      Ms [176][32] bf16 @25600 (11264) | Ss [7][24] f32 @36864 (672) = 37536 B
  __shared__ __align__(16) char smem[37536];
  unsigned short* Xs = (unsigned short*)(smem);
  unsigned short* Zs = (unsigned short*)(smem + 13312);
  unsigned short* Ms = (unsigned short*)(smem + 25600);
  float*          Ss = (float*)(smem + 36864);
  float*          B2 = (float*)(smem);           // epilogue reuse: [128][25] f32 = 12800 B

  f32x4 acc[2][6];                               // 48 AGPRs (was 96)
  #pragma unroll
  for (int i = 0; i < 2; ++i)
    #pragma unroll
    for (int j = 0; j < 6; ++j)
      acc[i][j] = (f32x4){0.f, 0.f, 0.f, 0.f};

  // ---- block init: M~[k][w][v] = M_k[v][w] bf16, zero-padded ----
  for (int i = tid; i < MROWS * 32; i += 256) {
    int row = i >> 5, v = i & 31;
    int k = row / 24, w = row - k * 24;
    float val = 0.f;
    if (row < 168 && w < 22 && v < 22)
      val = (k < 3) ? Ag[(k * 22 + v) * 22 + w]
                    : attA[(((n << 2) + (k - 3)) * 22 + v) * 22 + w];
    Ms[i] = f2bf_rn(val);
  }
  if (tid < 168) {                               // S[k][w] = sum_v M_k[v][w] (fp32 exact)
    int k = tid / 24, w = tid - k * 24;
    float s = 0.f;
    if (w < 22)
      for (int v = 0; v < 22; ++v)
        s += (k < 3) ? Ag[(k * 22 + v) * 22 + w]
                     : attA[(((n << 2) + (k - 3)) * 22 + v) * 22 + w];
    Ss[tid] = s;
  }
  for (int i = tid; i < 512; i += 256) Zs[88 * CHUNK + i] = 0;   // Ntile-5 pad rows
  for (int i = tid; i < 64 * XSTR / 2; i += 256) ((unsigned*)Xs)[i] = 0; // pads 0, not NaN
  __syncthreads();

  for (int chunk = 0; chunk < 4; ++chunk) {
    // ---- stage x[n, chunk*64..+64, tt*4..+4, :] -> Xs bf16 [ci][t*24+v] ----
    for (int i = tid; i < CHUNK * 22; i += 256) {
      int ci = i / 22, q = i - ci * 22;
      const float4 f4 = *(const float4*)(x + (size_t)((n * 256 + chunk * CHUNK + ci) * 11264)
                                           + tt * NTW + q * 4);
      float vv[4] = {f4.x, f4.y, f4.z, f4.w};
      int tv0 = q * 4;
      #pragma unroll
      for (int j = 0; j < 4; ++j) {
        int tv = tv0 + j;
        int t = tv / 22, v = tv - t * 22;
        Xs[ci * XSTR + t * 24 + v] = f2bf_rn(vv[j]);
      }
    }
    __syncthreads();

    for (int k = 0; k < 7; ++k) {
      // ---- W-frag prefetch (global; drained by barrier #1, consumed after) ----
      bf16x8 wf[2][2];
      #pragma unroll
      for (int s = 0; s < 2; ++s)
        #pragma unroll
        for (int mi = 0; mi < 2; ++mi) {
          int c = ch * 128 + (wave * 2 + mi) * 16 + l15;
          size_t idx = (size_t)((k * 256 + c) * 256) + chunk * CHUNK + s * 32 + l4 * 8;
          wf[s][mi] = USE_WB ? *(const bf16x8*)(Wb + idx) : ldw_f32(W + idx);
        }

      // ---- z phase: z[ci,w] = X[ci,v] @ M_k[v,w]; wave owns ci rows [wave*16,+16) ----
      bf16x8 bm0 = *(const bf16x8*)(&Ms[(k * 24 + l15) * 32 + l4 * 8]);
      bf16x8 bm1 = *(const bf16x8*)(&Ms[(k * 24 + 16 + l15) * 32 + l4 * 8]);
      const int ci0 = wave * 16 + l4 * 4;
      const int cb  = ci0 >> 3, sub = ci0 & 7;
      #pragma unroll
      for (int th = 0; th < 2; ++th) {           // t-halves cap live zt at 16 VGPRs
        f32x4 zt[2][2];
        #pragma unroll
        for (int t2 = 0; t2 < 2; ++t2) {
          int t = th * 2 + t2;
          bf16x8 ax = *(const bf16x8*)(&Xs[(wave * 16 + l15) * XSTR + t * 24 + l4 * 8]);
          zt[t2][0] = __builtin_amdgcn_mfma_f32_16x16x32_bf16(ax, bm0, (f32x4){0.f,0.f,0.f,0.f}, 0, 0, 0);
          zt[t2][1] = __builtin_amdgcn_mfma_f32_16x16x32_bf16(ax, bm1, (f32x4){0.f,0.f,0.f,0.f}, 0, 0, 0);
        }
        #pragma unroll
        for (int t2 = 0; t2 < 2; ++t2) {
          int t = th * 2 + t2;
          #pragma unroll
          for (int ni = 0; ni < 2; ++ni) {
            int w = ni * 16 + l15;
            if (w < 22) {
              int tw = t * 22 + w;
              int eo = tw * CHUNK + ((cb ^ (tw & 7)) << 3) + sub;
              f32x4 z = zt[t2][ni];
              u32x2 p; p[0] = pk_rh(z[0], z[1]); p[1] = pk_rh(z[2], z[3]);
              *(u32x2*)(&Zs[eo]) = p;            // 8 B aligned, ~2-way banks
            }
          }
        }
      }
      __syncthreads();

      // ---- main GEMM: out[c,tw] += Wk[c, ci-chunk] @ z ----
      #pragma unroll
      for (int s = 0; s < 2; ++s) {
        int cb2 = (s << 2) + l4;
        #pragma unroll
        for (int ni = 0; ni < 6; ++ni) {
          int tw = ni * 16 + l15;
          bf16x8 zf = *(const bf16x8*)(&Zs[tw * CHUNK + ((cb2 ^ (tw & 7)) << 3)]);
          #pragma unroll
          for (int mi = 0; mi < 2; ++mi)
            acc[mi][ni] = __builtin_amdgcn_mfma_f32_16x16x32_bf16(wf[s][mi], zf, acc[mi][ni], 0, 0, 0);
        }
      }
      __syncthreads();   // protects Zs overwrite (next k) / Xs overwrite (next chunk)
    }
  }

  // ---- bias2[c_local][w] = sum_k b[k*256+c] * S_k[w]  (Xs+Zs dead -> reuse) ----
  for (int i = tid; i < 128 * 22; i += 256) {
    int cl = i / 22, w = i - cl * 22;
    int c = ch * 128 + cl;
    float s = 0.f;
    #pragma unroll
    for (int k = 0; k < 7; ++k) s += b[k * 256 + c] * Ss[k * 24 + w];
    B2[cl * 25 + w] = s;
  }
  __syncthreads();

  // ---- epilogue: bias + store. C-layout: col=tw, row=l4*4+r ----
  int tg0 = tt * TT;
  #pragma unroll
  for (int ni = 0; ni < 6; ++ni) {
    int tw = ni * 16 + l15;
    if (tw < NTW) {
      int t = tw / 22, w = tw - t * 22;
      #pragma unroll
      for (int mi = 0; mi < 2; ++mi) {
        int cl0 = (wave * 2 + mi) * 16 + l4 * 4;
        #pragma unroll
        for (int r = 0; r < 4; ++r) {
          int cl = cl0 + r;
          int c = ch * 128 + cl;
          out[(size_t)((n * 256 + c) * 512 + tg0 + t) * 22 + w] = acc[mi][ni][r] + B2[cl * 25 + w];
        }
      }
    }
  }
}

extern "C" void kernel_launch(void* const* d_in, const int* in_sizes, int n_in,
                              void* d_out, int out_size, void* d_ws, size_t ws_size,
                              hipStream_t stream) {
  (void)in_sizes; (void)n_in; (void)out_size;
  const float* x    = (const float*)d_in[0];
  const float* Ag   = (const float*)d_in[1];
  const float* attA = (const float*)d_in[2];
  const float* W    = (const float*)d_in[3];
  const float* b    = (const float*)d_in[4];
  float* out = (float*)d_out;
  dim3 grid(128, 8, 2);    // (t-tiles, n, c-half)
  bool use_wb = (d_ws != nullptr) && (ws_size >= (size_t)WB_BYTES);
  if (use_wb) {
    unsigned short* Wb = (unsigned short*)d_ws;
    wconv<<<224, 256, 0, stream>>>(W, Wb);
    sgc_fused<true><<<grid, 256, 0, stream>>>(x, Ag, attA, W, Wb, b, out);
  } else {
    sgc_fused<false><<<grid, 256, 0, stream>>>(x, Ag, attA, W, nullptr, b, out);
  }
}